// Round 6
// baseline (148.869 us; speedup 1.0000x reference)
//
#include <hip/hip_runtime.h>
#include <math.h>

#define B_     2
#define N_     6890
#define NF_    2000
#define NFP_   2048     // padded triangles (32 chunks of 64)
#define NPT_   6912     // padded points: 27*256 = 54*128
#define OPP7_  7168     // padded opposite cloud: 28*256
#define TCG_   8        // tri-chunk groups   (block = 4 waves = 4 chunks of 64 tris)
#define OCG_   7        // opp-chunk groups   (block = 4 waves = 4 chunks of 256 opp)

// ---------------------------------------------------------------------------
// atan2(y,x)/(2*pi): single-rcp octant reduction, 1/2pi folded into poly.
// ---------------------------------------------------------------------------
__device__ __forceinline__ float atan2_o2pi(float y, float x) {
    float ax = __builtin_fabsf(x);
    float ay = __builtin_fabsf(y);
    float mx = fmaxf(ax, ay);
    float mn = fminf(ax, ay);
    bool  big = mn > 0.41421356f * mx;              // a > tan(pi/8)
    float num = big ? (mn - mx) : mn;
    float den = big ? (mn + mx) : mx;
    float t   = num * __builtin_amdgcn_rcpf(den);
    float z   = t * t;
    float p   = fmaf(fmaf(fmaf(1.2817932e-2f, z, -2.2087019e-2f), z,
                          3.1795514e-2f), z, -5.3051037e-2f);   // coeffs / 2pi
    float r   = t * fmaf(z, p, 0.15915494309f);     // atan(t)/2pi
    if (big)      r += 0.125f;
    if (ay > ax)  r  = 0.25f - r;
    if (x < 0.0f) r  = 0.5f  - r;
    return copysignf(r, y);
}

// ---------------------------------------------------------------------------
// prep:
//  pw[b][n] = (x,y,z,|p|^2)        pad zeros              [B][NPT_]
//  st[b][n] = (-2x,-2y,-2z,|o|^2)  pad (0,0,0,1e30)       [B][OPP7_]
//  tbl[b][f][20] = [A,B,C, -S, det0, na,nb,nc, qab,qbc,qca, 0]
//                  pad tris (1,1,1)x3 -> S=0, det0=0 -> angle exactly 0
// ---------------------------------------------------------------------------
__global__ void prep_kernel(const float* __restrict__ v1, const float* __restrict__ v2,
                            const int* __restrict__ faces,
                            float4* __restrict__ pw1, float4* __restrict__ pw2,
                            float4* __restrict__ st1, float4* __restrict__ st2,
                            float* __restrict__ tbl1, float* __restrict__ tbl2) {
    int tid = blockIdx.x * 256 + threadIdx.x;

    if (tid < B_ * NPT_) {
        int b = tid / NPT_, n = tid - b * NPT_;
        float4 q1 = make_float4(0.f, 0.f, 0.f, 0.f), q2 = q1;
        if (n < N_) {
            float x1 = v1[(b*N_+n)*3+0], y1 = v1[(b*N_+n)*3+1], z1 = v1[(b*N_+n)*3+2];
            float x2 = v2[(b*N_+n)*3+0], y2 = v2[(b*N_+n)*3+1], z2 = v2[(b*N_+n)*3+2];
            q1 = make_float4(x1, y1, z1, fmaf(x1,x1, fmaf(y1,y1, z1*z1)));
            q2 = make_float4(x2, y2, z2, fmaf(x2,x2, fmaf(y2,y2, z2*z2)));
        }
        pw1[tid] = q1; pw2[tid] = q2;
    }

    if (tid < B_ * OPP7_) {
        int b = tid / OPP7_, n = tid - b * OPP7_;
        float4 q1 = make_float4(0.f, 0.f, 0.f, 1e30f), q2 = q1;
        if (n < N_) {
            float x1 = v1[(b*N_+n)*3+0], y1 = v1[(b*N_+n)*3+1], z1 = v1[(b*N_+n)*3+2];
            float x2 = v2[(b*N_+n)*3+0], y2 = v2[(b*N_+n)*3+1], z2 = v2[(b*N_+n)*3+2];
            q1 = make_float4(-2.f*x1, -2.f*y1, -2.f*z1, fmaf(x1,x1, fmaf(y1,y1, z1*z1)));
            q2 = make_float4(-2.f*x2, -2.f*y2, -2.f*z2, fmaf(x2,x2, fmaf(y2,y2, z2*z2)));
        }
        st1[tid] = q1; st2[tid] = q2;
    }

    if (tid < 2 * B_ * NFP_) {
        int src = tid >> 12;
        int rr  = tid & (B_ * NFP_ - 1);
        int b   = rr >> 11;
        int f   = rr & (NFP_ - 1);
        const float* V = src ? v2 : v1;
        float Ax=1.f,Ay=1.f,Az=1.f,Bx=1.f,By=1.f,Bz=1.f,Cx=1.f,Cy=1.f,Cz=1.f;
        if (f < NF_) {
            int i0 = faces[f*3+0], i1 = faces[f*3+1], i2 = faces[f*3+2];
            Ax=V[(b*N_+i0)*3+0]; Ay=V[(b*N_+i0)*3+1]; Az=V[(b*N_+i0)*3+2];
            Bx=V[(b*N_+i1)*3+0]; By=V[(b*N_+i1)*3+1]; Bz=V[(b*N_+i1)*3+2];
            Cx=V[(b*N_+i2)*3+0]; Cy=V[(b*N_+i2)*3+1]; Cz=V[(b*N_+i2)*3+2];
        }
        float Sx = (Ay*Bz - Az*By) + (By*Cz - Bz*Cy) + (Cy*Az - Cz*Ay);
        float Sy = (Az*Bx - Ax*Bz) + (Bz*Cx - Bx*Cz) + (Cz*Ax - Cx*Az);
        float Sz = (Ax*By - Ay*Bx) + (Bx*Cy - By*Cx) + (Cx*Ay - Cy*Ax);
        float det0 = Ax*(By*Cz - Bz*Cy) + Ay*(Bz*Cx - Bx*Cz) + Az*(Bx*Cy - By*Cx);
        float na = Ax*Ax+Ay*Ay+Az*Az, nb = Bx*Bx+By*By+Bz*Bz, nc = Cx*Cx+Cy*Cy+Cz*Cz;
        float qab = Ax*Bx+Ay*By+Az*Bz, qbc = Bx*Cx+By*Cy+Bz*Cz, qca = Cx*Ax+Cy*Ay+Cz*Az;
        float* o = (src ? tbl2 : tbl1) + ((b << 11) + f) * 20;
        o[0]=Ax;  o[1]=Ay;  o[2]=Az;  o[3]=Bx;  o[4]=By;  o[5]=Bz;
        o[6]=Cx;  o[7]=Cy;  o[8]=Cz;  o[9]=-Sx; o[10]=-Sy; o[11]=-Sz;
        o[12]=det0; o[13]=na; o[14]=nb; o[15]=nc;
        o[16]=qab;  o[17]=qbc; o[18]=qca; o[19]=0.f;
    }
}

// ---------------------------------------------------------------------------
// winding (systolic): lane = triangle, record in 20 VGPRs (loaded once).
// A 64-point batch (float4 + f32 acc) rotates lane->lane via __shfl.
// Block = 4 waves = 4 tri-chunks over the same 128 points; LDS cross-wave sum.
// grid: (db*TCG_ + tcg)*54 + pg  = 1728 blocks.
// ---------------------------------------------------------------------------
__global__ __launch_bounds__(256) void winding_kernel(
        const float4* __restrict__ pw1, const float4* __restrict__ pw2,
        const float* __restrict__ tbl1, const float* __restrict__ tbl2,
        float* __restrict__ part) {
    __shared__ float sacc[256];
    int bid = blockIdx.x;
    int pg  = bid % 54;  int r = bid / 54;
    int tcg = r % TCG_;  int db = r / TCG_;
    int b = db & 1, dir = db >> 1;
    int wid = threadIdx.x >> 6, lane = threadIdx.x & 63;

    const float4* pw  = dir ? pw2 : pw1;          // own points
    const float*  tbl = dir ? tbl1 : tbl2;        // opposite mesh table
    const float4* rec = (const float4*)(tbl + (b * NFP_ + (tcg*4 + wid)*64 + lane) * 20);
    float4 r0 = rec[0], r1 = rec[1], r2 = rec[2], r3 = rec[3], r4 = rec[4];
    // r0=(Ax,Ay,Az,Bx) r1=(By,Bz,Cx,Cy) r2=(Cz,-Sx,-Sy,-Sz)
    // r3=(det0,na,nb,nc) r4=(qab,qbc,qca,0)

    int src = (lane + 1) & 63;

    for (int batch = 0; batch < 2; ++batch) {
        int n0 = pg * 128 + batch * 64;
        float4 P = pw[b * NPT_ + n0 + lane];
        float acc = 0.f;
        #pragma unroll 2
        for (int k = 0; k < 64; ++k) {
            float dAp = fmaf(r0.x,P.x, fmaf(r0.y,P.y, r0.z*P.z));
            float dBp = fmaf(r0.w,P.x, fmaf(r1.x,P.y, r1.y*P.z));
            float dCp = fmaf(r1.z,P.x, fmaf(r1.w,P.y, r2.x*P.z));
            float det = fmaf(r2.y,P.x, fmaf(r2.z,P.y, fmaf(r2.w,P.z, r3.x)));
            float la2 = fmaxf(fmaf(-2.f, dAp, r3.y + P.w), 0.f);
            float lb2 = fmaxf(fmaf(-2.f, dBp, r3.z + P.w), 0.f);
            float lc2 = fmaxf(fmaf(-2.f, dCp, r3.w + P.w), 0.f);
            float la = __builtin_amdgcn_sqrtf(la2);
            float lb = __builtin_amdgcn_sqrtf(lb2);
            float lc = __builtin_amdgcn_sqrtf(lc2);
            float dab = (r4.x + P.w) - (dAp + dBp);
            float dbc = (r4.y + P.w) - (dBp + dCp);
            float dca = (r4.z + P.w) - (dCp + dAp);
            float denom = fmaf(fmaf(la, lb, dab), lc, fmaf(dbc, la, dca * lb));
            acc += atan2_o2pi(det, denom);
            // rotate point + accumulator to neighbor lane
            float px = __shfl(P.x, src, 64);
            float py = __shfl(P.y, src, 64);
            float pz = __shfl(P.z, src, 64);
            float pq = __shfl(P.w, src, 64);
            float an = __shfl(acc, src, 64);
            P = make_float4(px, py, pz, pq);
            acc = an;
        }
        sacc[threadIdx.x] = acc;
        __syncthreads();
        if (wid == 0) {
            float s = (sacc[lane] + sacc[64+lane]) + (sacc[128+lane] + sacc[192+lane]);
            part[(db*TCG_ + tcg)*NPT_ + n0 + lane] = s;
        }
        __syncthreads();
    }
}

// ---------------------------------------------------------------------------
// rowmin (systolic): lane = 4 opposite records (fixed, 16 VGPRs); own point +
// running min rotate. Block = 4 waves = 4 opp-chunks over same 128 points.
// grid: (db*OCG_ + ocg)*54 + pg = 1512 blocks.
// ---------------------------------------------------------------------------
__global__ __launch_bounds__(256) void rowmin_kernel(
        const float4* __restrict__ pw1, const float4* __restrict__ pw2,
        const float4* __restrict__ st1, const float4* __restrict__ st2,
        float* __restrict__ rmp) {
    __shared__ float smin[256];
    int bid = blockIdx.x;
    int pg  = bid % 54;  int r = bid / 54;
    int ocg = r % OCG_;  int db = r / OCG_;
    int b = db & 1, dir = db >> 1;
    int wid = threadIdx.x >> 6, lane = threadIdx.x & 63;

    const float4* pw = dir ? pw2 : pw1;           // own cloud
    const float4* st = dir ? st1 : st2;           // opposite records
    const float4* qb = st + b * OPP7_ + (ocg*4 + wid) * 256;
    float4 q0 = qb[lane], q1 = qb[64+lane], q2 = qb[128+lane], q3 = qb[192+lane];

    int src = (lane + 1) & 63;

    for (int batch = 0; batch < 2; ++batch) {
        int n0 = pg * 128 + batch * 64;
        float4 P = pw[b * NPT_ + n0 + lane];
        float m = 3.4e38f;
        #pragma unroll 4
        for (int k = 0; k < 64; ++k) {
            float d0 = fmaf(q0.x,P.x, fmaf(q0.y,P.y, fmaf(q0.z,P.z, q0.w + P.w)));
            float d1 = fmaf(q1.x,P.x, fmaf(q1.y,P.y, fmaf(q1.z,P.z, q1.w + P.w)));
            float d2 = fmaf(q2.x,P.x, fmaf(q2.y,P.y, fmaf(q2.z,P.z, q2.w + P.w)));
            float d3 = fmaf(q3.x,P.x, fmaf(q3.y,P.y, fmaf(q3.z,P.z, q3.w + P.w)));
            m = fminf(m, fminf(fminf(d0, d1), fminf(d2, d3)));
            float px = __shfl(P.x, src, 64);
            float py = __shfl(P.y, src, 64);
            float pz = __shfl(P.z, src, 64);
            float pq = __shfl(P.w, src, 64);
            float mn = __shfl(m,   src, 64);
            P = make_float4(px, py, pz, pq);
            m = mn;
        }
        smin[threadIdx.x] = m;
        __syncthreads();
        if (wid == 0) {
            float mm = fminf(fminf(smin[lane], smin[64+lane]),
                             fminf(smin[128+lane], smin[192+lane]));
            rmp[(db*OCG_ + ocg)*NPT_ + n0 + lane] = mm;
        }
        __syncthreads();
    }
}

// ---------------------------------------------------------------------------
// fold: per (db, 256-point group): sum 8 winding partials, min 7 rowmin
// partials, then block-reduce masked stats -> pstat[db*27+pg].
// ---------------------------------------------------------------------------
__global__ __launch_bounds__(256) void fold_kernel(
        const float* __restrict__ part, const float* __restrict__ rmp,
        float4* __restrict__ pstat) {
    int pg = blockIdx.x % 27, db = blockIdx.x / 27;
    int t = threadIdx.x, n = pg * 256 + t;

    float ws = 0.f;
    #pragma unroll
    for (int g = 0; g < TCG_; ++g) ws += part[(db*TCG_ + g)*NPT_ + n];
    float rv = 3.4e38f;
    #pragma unroll
    for (int g = 0; g < OCG_; ++g) rv = fminf(rv, rmp[(db*OCG_ + g)*NPT_ + n]);

    bool valid = n < N_;
    float d = sqrtf(rv);
    bool msk = valid && (ws >= 0.99f);
    float v_min = valid ? d : 3.4e38f;
    float v_max = msk ? d : -3.4e38f;
    float v_sum = msk ? d : 0.f;
    float v_cnt = msk ? 1.f : 0.f;

    #pragma unroll
    for (int off = 32; off; off >>= 1) {
        v_min = fminf(v_min, __shfl_down(v_min, off, 64));
        v_max = fmaxf(v_max, __shfl_down(v_max, off, 64));
        v_sum += __shfl_down(v_sum, off, 64);
        v_cnt += __shfl_down(v_cnt, off, 64);
    }
    __shared__ float4 sred[4];
    int wid = t >> 6, lane = t & 63;
    if (lane == 0) sred[wid] = make_float4(v_min, v_max, v_sum, v_cnt);
    __syncthreads();
    if (t == 0) {
        float4 a = sred[0], bb = sred[1], c = sred[2], dd = sred[3];
        pstat[db*27 + pg] = make_float4(
            fminf(fminf(a.x, bb.x), fminf(c.x, dd.x)),
            fmaxf(fmaxf(a.y, bb.y), fmaxf(c.y, dd.y)),
            (a.z + bb.z) + (c.z + dd.z),
            (a.w + bb.w) + (c.w + dd.w));
    }
}

// ---------------------------------------------------------------------------
// final: 1 block, wave w reduces db=w's 27 group stats; thread 0 writes [5][B].
// ---------------------------------------------------------------------------
__global__ void final_kernel(const float4* __restrict__ pstat, float* __restrict__ out) {
    int t = threadIdx.x, wid = t >> 6, lane = t & 63;    // wid = db
    float4 v = make_float4(3.4e38f, -3.4e38f, 0.f, 0.f);
    if (lane < 27) v = pstat[wid*27 + lane];
    #pragma unroll
    for (int off = 32; off; off >>= 1) {
        v.x = fminf(v.x, __shfl_down(v.x, off, 64));
        v.y = fmaxf(v.y, __shfl_down(v.y, off, 64));
        v.z += __shfl_down(v.z, off, 64);
        v.w += __shfl_down(v.w, off, 64);
    }
    __shared__ float4 res[4];
    if (lane == 0) res[wid] = v;
    __syncthreads();
    if (t == 0) {
        #pragma unroll
        for (int b = 0; b < B_; ++b) {
            float4 s1 = res[b], s2 = res[2 + b];
            out[0 + b] = s1.x;
            out[2 + b] = (s1.w > 0.f) ? s1.y : 0.f;
            out[4 + b] = (s1.w > 0.f) ? (s1.z / s1.w) : 0.f;
            out[6 + b] = (s2.w > 0.f) ? s2.y : 0.f;
            out[8 + b] = (s2.w > 0.f) ? (s2.z / s2.w) : 0.f;
        }
    }
}

extern "C" void kernel_launch(void* const* d_in, const int* in_sizes, int n_in,
                              void* d_out, int out_size, void* d_ws, size_t ws_size,
                              hipStream_t stream) {
    const float* v1    = (const float*)d_in[0];
    const float* v2    = (const float*)d_in[1];
    const int*   faces = (const int*)d_in[2];

    float4* f4 = (float4*)d_ws;
    float4* pw1   = f4;                         // B*NPT_  = 13824 f4
    float4* pw2   = pw1 + B_ * NPT_;
    float4* st1   = pw2 + B_ * NPT_;            // B*OPP7_ = 14336 f4
    float4* st2   = st1 + B_ * OPP7_;
    float4* pstat = st2 + B_ * OPP7_;           // 108 f4
    float*  tbl1  = (float*)(pstat + 128);      // B*NFP_*20 = 81920 f
    float*  tbl2  = tbl1 + B_ * NFP_ * 20;
    float*  part  = tbl2 + B_ * NFP_ * 20;      // 4*TCG_*NPT_ = 221184 f
    float*  rmp   = part + 4 * TCG_ * NPT_;     // 4*OCG_*NPT_ = 193536 f
                                                // total ~3.2 MB

    float* out = (float*)d_out;

    prep_kernel<<<(B_ * OPP7_ + 255) / 256, 256, 0, stream>>>(
        v1, v2, faces, pw1, pw2, st1, st2, tbl1, tbl2);

    winding_kernel<<<4 * TCG_ * 54, 256, 0, stream>>>(pw1, pw2, tbl1, tbl2, part);

    rowmin_kernel<<<4 * OCG_ * 54, 256, 0, stream>>>(pw1, pw2, st1, st2, rmp);

    fold_kernel<<<4 * 27, 256, 0, stream>>>(part, rmp, pstat);

    final_kernel<<<1, 256, 0, stream>>>(pstat, out);
}

// Round 7
// 122.669 us; speedup vs baseline: 1.2136x; 1.2136x over previous
//
#include <hip/hip_runtime.h>
#include <math.h>

#define B_     2
#define N_     6890
#define NF_    2000
#define NFP_   2048     // padded triangles: 8 chunks x 256
#define NPT_   6912     // padded points: 108*64 = 27*256
#define OPP7_  7168     // padded opposite cloud: 7 chunks x 1024
#define TCG_   8        // tri chunks (256 tris, 4 recs/lane)
#define OCG_   7        // opp chunks (1024 recs, 16 recs/lane)

// ---------------------------------------------------------------------------
// atan2(y,x)/(2*pi): branchless octant reduction, single rcp, scale folded in.
// ---------------------------------------------------------------------------
__device__ __forceinline__ float atan2_o2pi(float y, float x) {
    float ax = __builtin_fabsf(x);
    float ay = __builtin_fabsf(y);
    float mx = fmaxf(ax, ay);
    float mn = fminf(ax, ay);
    bool  big = mn > 0.41421356f * mx;
    float num = big ? (mn - mx) : mn;
    float den = big ? (mn + mx) : mx;
    float t   = num * __builtin_amdgcn_rcpf(den);
    float z   = t * t;
    float p   = fmaf(fmaf(fmaf(1.2817932e-2f, z, -2.2087019e-2f), z,
                          3.1795514e-2f), z, -5.3051037e-2f);   // coeffs / 2pi
    float r   = fmaf(t, fmaf(z, p, 0.15915494309f), big ? 0.125f : 0.0f);
    r = (ay > ax)  ? 0.25f - r : r;
    r = (x < 0.0f) ? 0.5f  - r : r;
    return copysignf(r, y);
}

// ---------------------------------------------------------------------------
// prep (unchanged layouts):
//  pw[b][n] = (x,y,z,|p|^2)        pad zeros              [B][NPT_]
//  st[b][n] = (-2x,-2y,-2z,|o|^2)  pad (0,0,0,1e30)       [B][OPP7_]
//  tbl[b][f][20] = [A,B,C, -S, det0, na,nb,nc, qab,qbc,qca, 0]
// ---------------------------------------------------------------------------
__global__ void prep_kernel(const float* __restrict__ v1, const float* __restrict__ v2,
                            const int* __restrict__ faces,
                            float4* __restrict__ pw1, float4* __restrict__ pw2,
                            float4* __restrict__ st1, float4* __restrict__ st2,
                            float* __restrict__ tbl1, float* __restrict__ tbl2) {
    int tid = blockIdx.x * 256 + threadIdx.x;

    if (tid < B_ * NPT_) {
        int b = tid / NPT_, n = tid - b * NPT_;
        float4 q1 = make_float4(0.f, 0.f, 0.f, 0.f), q2 = q1;
        if (n < N_) {
            float x1 = v1[(b*N_+n)*3+0], y1 = v1[(b*N_+n)*3+1], z1 = v1[(b*N_+n)*3+2];
            float x2 = v2[(b*N_+n)*3+0], y2 = v2[(b*N_+n)*3+1], z2 = v2[(b*N_+n)*3+2];
            q1 = make_float4(x1, y1, z1, fmaf(x1,x1, fmaf(y1,y1, z1*z1)));
            q2 = make_float4(x2, y2, z2, fmaf(x2,x2, fmaf(y2,y2, z2*z2)));
        }
        pw1[tid] = q1; pw2[tid] = q2;
    }

    if (tid < B_ * OPP7_) {
        int b = tid / OPP7_, n = tid - b * OPP7_;
        float4 q1 = make_float4(0.f, 0.f, 0.f, 1e30f), q2 = q1;
        if (n < N_) {
            float x1 = v1[(b*N_+n)*3+0], y1 = v1[(b*N_+n)*3+1], z1 = v1[(b*N_+n)*3+2];
            float x2 = v2[(b*N_+n)*3+0], y2 = v2[(b*N_+n)*3+1], z2 = v2[(b*N_+n)*3+2];
            q1 = make_float4(-2.f*x1, -2.f*y1, -2.f*z1, fmaf(x1,x1, fmaf(y1,y1, z1*z1)));
            q2 = make_float4(-2.f*x2, -2.f*y2, -2.f*z2, fmaf(x2,x2, fmaf(y2,y2, z2*z2)));
        }
        st1[tid] = q1; st2[tid] = q2;
    }

    if (tid < 2 * B_ * NFP_) {
        int src = tid >> 12;
        int rr  = tid & (B_ * NFP_ - 1);
        int b   = rr >> 11;
        int f   = rr & (NFP_ - 1);
        const float* V = src ? v2 : v1;
        float Ax=1.f,Ay=1.f,Az=1.f,Bx=1.f,By=1.f,Bz=1.f,Cx=1.f,Cy=1.f,Cz=1.f;
        if (f < NF_) {
            int i0 = faces[f*3+0], i1 = faces[f*3+1], i2 = faces[f*3+2];
            Ax=V[(b*N_+i0)*3+0]; Ay=V[(b*N_+i0)*3+1]; Az=V[(b*N_+i0)*3+2];
            Bx=V[(b*N_+i1)*3+0]; By=V[(b*N_+i1)*3+1]; Bz=V[(b*N_+i1)*3+2];
            Cx=V[(b*N_+i2)*3+0]; Cy=V[(b*N_+i2)*3+1]; Cz=V[(b*N_+i2)*3+2];
        }
        float Sx = (Ay*Bz - Az*By) + (By*Cz - Bz*Cy) + (Cy*Az - Cz*Ay);
        float Sy = (Az*Bx - Ax*Bz) + (Bz*Cx - Bx*Cz) + (Cz*Ax - Cx*Az);
        float Sz = (Ax*By - Ay*Bx) + (Bx*Cy - By*Cx) + (Cx*Ay - Cy*Ax);
        float det0 = Ax*(By*Cz - Bz*Cy) + Ay*(Bz*Cx - Bx*Cz) + Az*(Bx*Cy - By*Cx);
        float na = Ax*Ax+Ay*Ay+Az*Az, nb = Bx*Bx+By*By+Bz*Bz, nc = Cx*Cx+Cy*Cy+Cz*Cz;
        float qab = Ax*Bx+Ay*By+Az*Bz, qbc = Bx*Cx+By*Cy+Bz*Cz, qca = Cx*Ax+Cy*Ay+Cz*Az;
        float* o = (src ? tbl2 : tbl1) + ((b << 11) + f) * 20;
        o[0]=Ax;  o[1]=Ay;  o[2]=Az;  o[3]=Bx;  o[4]=By;  o[5]=Bz;
        o[6]=Cx;  o[7]=Cy;  o[8]=Cz;  o[9]=-Sx; o[10]=-Sy; o[11]=-Sz;
        o[12]=det0; o[13]=na; o[14]=nb; o[15]=nc;
        o[16]=qab;  o[17]=qbc; o[18]=qca; o[19]=0.f;
    }
}

// per-record solid-angle/2pi given point P(x,y,z) and s=|p|^2 in scope
#define ANG(u0,u1,u2,u3,u4) ({                                               \
    float dAp = fmaf(u0.x,P.x, fmaf(u0.y,P.y, u0.z*P.z));                    \
    float dBp = fmaf(u0.w,P.x, fmaf(u1.x,P.y, u1.y*P.z));                    \
    float dCp = fmaf(u1.z,P.x, fmaf(u1.w,P.y, u2.x*P.z));                    \
    float det = fmaf(u2.y,P.x, fmaf(u2.z,P.y, fmaf(u2.w,P.z, u3.x)));        \
    float la = __builtin_amdgcn_sqrtf(fmaxf(fmaf(-2.f,dAp,u3.y+s),0.f));     \
    float lb = __builtin_amdgcn_sqrtf(fmaxf(fmaf(-2.f,dBp,u3.z+s),0.f));     \
    float lc = __builtin_amdgcn_sqrtf(fmaxf(fmaf(-2.f,dCp,u3.w+s),0.f));     \
    float dab = (u4.x+s)-(dAp+dBp);                                          \
    float dbc = (u4.y+s)-(dBp+dCp);                                          \
    float dca = (u4.z+s)-(dCp+dAp);                                          \
    float denom = fmaf(fmaf(la,lb,dab),lc, fmaf(dbc,la,dca*lb));             \
    atan2_o2pi(det, denom); })

// ---------------------------------------------------------------------------
// winding: lane holds 4 triangle records (80 VGPR); point batch (64 pts) in
// LDS; per iter: 1 ds_read_b128 (point) + 1 bpermute (acc) per 4 pairs.
// grid: (db*TCG_ + cg)*27 + pgrp = 864 blocks; wave w = batch pgrp*4+w.
// ---------------------------------------------------------------------------
__global__ __launch_bounds__(256) void winding_kernel(
        const float4* __restrict__ pw1, const float4* __restrict__ pw2,
        const float* __restrict__ tbl1, const float* __restrict__ tbl2,
        float* __restrict__ part) {
    __shared__ float4 pts[256];
    int bid  = blockIdx.x;
    int pgrp = bid % 27;
    int r    = bid / 27;
    int cg   = r & 7, db = r >> 3;
    int b = db & 1, dir = db >> 1;
    int t = threadIdx.x, wid = t >> 6, lane = t & 63;

    const float4* pw  = dir ? pw2 : pw1;
    const float*  tbl = dir ? tbl1 : tbl2;

    pts[t] = pw[b * NPT_ + pgrp * 256 + t];
    __syncthreads();

#define LREC(nm, j)                                                          \
    const float4* rp##nm = (const float4*)(tbl + (size_t)(b*NFP_ + cg*256 + j*64 + lane)*20); \
    float4 nm##0 = rp##nm[0], nm##1 = rp##nm[1], nm##2 = rp##nm[2],          \
           nm##3 = rp##nm[3], nm##4 = rp##nm[4];
    LREC(A, 0) LREC(Bq, 1) LREC(C, 2) LREC(D, 3)
#undef LREC

    const float4* mypts = pts + wid * 64;
    float acc = 0.f;
    int srcl = (lane + 1) & 63;
    #pragma unroll 2
    for (int k = 0; k < 64; ++k) {
        float4 P = mypts[(lane + k) & 63];
        float s = P.w;
        float g0 = ANG(A0,A1,A2,A3,A4);
        float g1 = ANG(Bq0,Bq1,Bq2,Bq3,Bq4);
        float g2 = ANG(C0,C1,C2,C3,C4);
        float g3 = ANG(D0,D1,D2,D3,D4);
        acc += (g0 + g1) + (g2 + g3);
        acc = __shfl(acc, srcl, 64);
    }
    part[(db*TCG_ + cg)*NPT_ + pgrp*256 + wid*64 + lane] = acc;
}

// ---------------------------------------------------------------------------
// rowmin: lane holds 16 opposite records (64 VGPR); own-point batch in LDS;
// per iter: 1 ds_read_b128 + 1 bpermute per 16 pairs.
// grid: (db*OCG_ + ocg)*27 + pgrp = 756 blocks.
// ---------------------------------------------------------------------------
__global__ __launch_bounds__(256) void rowmin_kernel(
        const float4* __restrict__ pw1, const float4* __restrict__ pw2,
        const float4* __restrict__ st1, const float4* __restrict__ st2,
        float* __restrict__ rmp) {
    __shared__ float4 pts[256];
    int bid  = blockIdx.x;
    int pgrp = bid % 27;
    int r    = bid / 27;
    int ocg  = r % OCG_, db = r / OCG_;
    int b = db & 1, dir = db >> 1;
    int t = threadIdx.x, wid = t >> 6, lane = t & 63;

    const float4* pw = dir ? pw2 : pw1;        // own cloud
    const float4* st = dir ? st1 : st2;        // opposite records

    pts[t] = pw[b * NPT_ + pgrp * 256 + t];
    __syncthreads();

    const float4* qb = st + b * OPP7_ + ocg * 1024;
#define LQ(j) float4 q##j = qb[j*64 + lane];
    LQ(0) LQ(1) LQ(2) LQ(3) LQ(4) LQ(5) LQ(6) LQ(7)
    LQ(8) LQ(9) LQ(10) LQ(11) LQ(12) LQ(13) LQ(14) LQ(15)
#undef LQ

    const float4* mypts = pts + wid * 64;
    float m = 3.4e38f;
    int srcl = (lane + 1) & 63;
    #pragma unroll 2
    for (int k = 0; k < 64; ++k) {
        float4 P = mypts[(lane + k) & 63];
        float s = P.w;
#define DD(j) float d##j = fmaf(q##j.x,P.x, fmaf(q##j.y,P.y, fmaf(q##j.z,P.z, q##j.w + s)));
        DD(0) DD(1) DD(2) DD(3) DD(4) DD(5) DD(6) DD(7)
        DD(8) DD(9) DD(10) DD(11) DD(12) DD(13) DD(14) DD(15)
#undef DD
        float e0 = fminf(d0,d1),  e1 = fminf(d2,d3),  e2 = fminf(d4,d5),  e3 = fminf(d6,d7);
        float e4 = fminf(d8,d9),  e5 = fminf(d10,d11), e6 = fminf(d12,d13), e7 = fminf(d14,d15);
        float f0 = fminf(e0,e1), f1 = fminf(e2,e3), f2 = fminf(e4,e5), f3 = fminf(e6,e7);
        m = fminf(m, fminf(fminf(f0,f1), fminf(f2,f3)));
        m = __shfl(m, srcl, 64);
    }
    rmp[(db*OCG_ + ocg)*NPT_ + pgrp*256 + wid*64 + lane] = m;
}

// ---------------------------------------------------------------------------
// fold: per (db, 256-point group): sum 8 winding partials, min 7 rowmin
// partials, block-reduce masked stats -> pstat[db*27+pg].
// ---------------------------------------------------------------------------
__global__ __launch_bounds__(256) void fold_kernel(
        const float* __restrict__ part, const float* __restrict__ rmp,
        float4* __restrict__ pstat) {
    int pg = blockIdx.x % 27, db = blockIdx.x / 27;
    int t = threadIdx.x, n = pg * 256 + t;

    float ws = 0.f;
    #pragma unroll
    for (int g = 0; g < TCG_; ++g) ws += part[(db*TCG_ + g)*NPT_ + n];
    float rv = 3.4e38f;
    #pragma unroll
    for (int g = 0; g < OCG_; ++g) rv = fminf(rv, rmp[(db*OCG_ + g)*NPT_ + n]);

    bool valid = n < N_;
    float d = sqrtf(rv);
    bool msk = valid && (ws >= 0.99f);
    float v_min = valid ? d : 3.4e38f;
    float v_max = msk ? d : -3.4e38f;
    float v_sum = msk ? d : 0.f;
    float v_cnt = msk ? 1.f : 0.f;

    #pragma unroll
    for (int off = 32; off; off >>= 1) {
        v_min = fminf(v_min, __shfl_down(v_min, off, 64));
        v_max = fmaxf(v_max, __shfl_down(v_max, off, 64));
        v_sum += __shfl_down(v_sum, off, 64);
        v_cnt += __shfl_down(v_cnt, off, 64);
    }
    __shared__ float4 sred[4];
    int wid = t >> 6, lane = t & 63;
    if (lane == 0) sred[wid] = make_float4(v_min, v_max, v_sum, v_cnt);
    __syncthreads();
    if (t == 0) {
        float4 a = sred[0], bb = sred[1], c = sred[2], dd = sred[3];
        pstat[db*27 + pg] = make_float4(
            fminf(fminf(a.x, bb.x), fminf(c.x, dd.x)),
            fmaxf(fmaxf(a.y, bb.y), fmaxf(c.y, dd.y)),
            (a.z + bb.z) + (c.z + dd.z),
            (a.w + bb.w) + (c.w + dd.w));
    }
}

// ---------------------------------------------------------------------------
// final: 1 block, wave w reduces db=w's 27 group stats; thread 0 writes [5][B].
// ---------------------------------------------------------------------------
__global__ void final_kernel(const float4* __restrict__ pstat, float* __restrict__ out) {
    int t = threadIdx.x, wid = t >> 6, lane = t & 63;    // wid = db
    float4 v = make_float4(3.4e38f, -3.4e38f, 0.f, 0.f);
    if (lane < 27) v = pstat[wid*27 + lane];
    #pragma unroll
    for (int off = 32; off; off >>= 1) {
        v.x = fminf(v.x, __shfl_down(v.x, off, 64));
        v.y = fmaxf(v.y, __shfl_down(v.y, off, 64));
        v.z += __shfl_down(v.z, off, 64);
        v.w += __shfl_down(v.w, off, 64);
    }
    __shared__ float4 res[4];
    if (lane == 0) res[wid] = v;
    __syncthreads();
    if (t == 0) {
        #pragma unroll
        for (int b = 0; b < B_; ++b) {
            float4 s1 = res[b], s2 = res[2 + b];
            out[0 + b] = s1.x;
            out[2 + b] = (s1.w > 0.f) ? s1.y : 0.f;
            out[4 + b] = (s1.w > 0.f) ? (s1.z / s1.w) : 0.f;
            out[6 + b] = (s2.w > 0.f) ? s2.y : 0.f;
            out[8 + b] = (s2.w > 0.f) ? (s2.z / s2.w) : 0.f;
        }
    }
}

extern "C" void kernel_launch(void* const* d_in, const int* in_sizes, int n_in,
                              void* d_out, int out_size, void* d_ws, size_t ws_size,
                              hipStream_t stream) {
    const float* v1    = (const float*)d_in[0];
    const float* v2    = (const float*)d_in[1];
    const int*   faces = (const int*)d_in[2];

    float4* f4 = (float4*)d_ws;
    float4* pw1   = f4;                         // B*NPT_  = 13824 f4
    float4* pw2   = pw1 + B_ * NPT_;
    float4* st1   = pw2 + B_ * NPT_;            // B*OPP7_ = 14336 f4
    float4* st2   = st1 + B_ * OPP7_;
    float4* pstat = st2 + B_ * OPP7_;           // 108 f4
    float*  tbl1  = (float*)(pstat + 128);      // B*NFP_*20 = 81920 f
    float*  tbl2  = tbl1 + B_ * NFP_ * 20;
    float*  part  = tbl2 + B_ * NFP_ * 20;      // 4*TCG_*NPT_ = 221184 f
    float*  rmp   = part + 4 * TCG_ * NPT_;     // 4*OCG_*NPT_ = 193536 f
                                                // total ~3.2 MB

    float* out = (float*)d_out;

    prep_kernel<<<(B_ * OPP7_ + 255) / 256, 256, 0, stream>>>(
        v1, v2, faces, pw1, pw2, st1, st2, tbl1, tbl2);

    winding_kernel<<<4 * TCG_ * 27, 256, 0, stream>>>(pw1, pw2, tbl1, tbl2, part);

    rowmin_kernel<<<4 * OCG_ * 27, 256, 0, stream>>>(pw1, pw2, st1, st2, rmp);

    fold_kernel<<<4 * 27, 256, 0, stream>>>(part, rmp, pstat);

    final_kernel<<<1, 256, 0, stream>>>(pstat, out);
}

// Round 8
// 114.504 us; speedup vs baseline: 1.3001x; 1.0713x over previous
//
#include <hip/hip_runtime.h>
#include <math.h>

#define B_     2
#define N_     6890
#define NF_    2000
#define NFP_   2048     // padded triangles: 16 chunks x 128
#define NPT_   6912     // padded points: 27*256
#define OPP7_  7168     // padded opposite cloud: 7 chunks x 1024
#define TCG_   16       // tri chunks (128 tris each, 2 recs/lane)
#define OCG_   7        // opp chunks (1024 recs each, 16 recs/lane)
#define WBLK_  (4 * TCG_ * 27)   // 1728 winding blocks
#define RBLK_  (4 * OCG_ * 27)   // 756  rowmin blocks

// ---------------------------------------------------------------------------
// atan2(y,x)/(2*pi): branchless octant reduction, single rcp, scale folded in.
// ---------------------------------------------------------------------------
__device__ __forceinline__ float atan2_o2pi(float y, float x) {
    float ax = __builtin_fabsf(x);
    float ay = __builtin_fabsf(y);
    float mx = fmaxf(ax, ay);
    float mn = fminf(ax, ay);
    bool  big = mn > 0.41421356f * mx;
    float num = big ? (mn - mx) : mn;
    float den = big ? (mn + mx) : mx;
    float t   = num * __builtin_amdgcn_rcpf(den);
    float z   = t * t;
    float p   = fmaf(fmaf(fmaf(1.2817932e-2f, z, -2.2087019e-2f), z,
                          3.1795514e-2f), z, -5.3051037e-2f);   // coeffs / 2pi
    float r   = fmaf(t, fmaf(z, p, 0.15915494309f), big ? 0.125f : 0.0f);
    r = (ay > ax)  ? 0.25f - r : r;
    r = (x < 0.0f) ? 0.5f  - r : r;
    return copysignf(r, y);
}

// ---------------------------------------------------------------------------
// prep (layouts unchanged):
//  pw[b][n] = (x,y,z,|p|^2)        pad zeros              [B][NPT_]
//  st[b][n] = (-2x,-2y,-2z,|o|^2)  pad (0,0,0,1e30)       [B][OPP7_]
//  tbl[b][f][20] = [A,B,C, -S, det0, na,nb,nc, qab,qbc,qca, 0]
// ---------------------------------------------------------------------------
__global__ void prep_kernel(const float* __restrict__ v1, const float* __restrict__ v2,
                            const int* __restrict__ faces,
                            float4* __restrict__ pw1, float4* __restrict__ pw2,
                            float4* __restrict__ st1, float4* __restrict__ st2,
                            float* __restrict__ tbl1, float* __restrict__ tbl2) {
    int tid = blockIdx.x * 256 + threadIdx.x;

    if (tid < B_ * NPT_) {
        int b = tid / NPT_, n = tid - b * NPT_;
        float4 q1 = make_float4(0.f, 0.f, 0.f, 0.f), q2 = q1;
        if (n < N_) {
            float x1 = v1[(b*N_+n)*3+0], y1 = v1[(b*N_+n)*3+1], z1 = v1[(b*N_+n)*3+2];
            float x2 = v2[(b*N_+n)*3+0], y2 = v2[(b*N_+n)*3+1], z2 = v2[(b*N_+n)*3+2];
            q1 = make_float4(x1, y1, z1, fmaf(x1,x1, fmaf(y1,y1, z1*z1)));
            q2 = make_float4(x2, y2, z2, fmaf(x2,x2, fmaf(y2,y2, z2*z2)));
        }
        pw1[tid] = q1; pw2[tid] = q2;
    }

    if (tid < B_ * OPP7_) {
        int b = tid / OPP7_, n = tid - b * OPP7_;
        float4 q1 = make_float4(0.f, 0.f, 0.f, 1e30f), q2 = q1;
        if (n < N_) {
            float x1 = v1[(b*N_+n)*3+0], y1 = v1[(b*N_+n)*3+1], z1 = v1[(b*N_+n)*3+2];
            float x2 = v2[(b*N_+n)*3+0], y2 = v2[(b*N_+n)*3+1], z2 = v2[(b*N_+n)*3+2];
            q1 = make_float4(-2.f*x1, -2.f*y1, -2.f*z1, fmaf(x1,x1, fmaf(y1,y1, z1*z1)));
            q2 = make_float4(-2.f*x2, -2.f*y2, -2.f*z2, fmaf(x2,x2, fmaf(y2,y2, z2*z2)));
        }
        st1[tid] = q1; st2[tid] = q2;
    }

    if (tid < 2 * B_ * NFP_) {
        int src = tid >> 12;
        int rr  = tid & (B_ * NFP_ - 1);
        int b   = rr >> 11;
        int f   = rr & (NFP_ - 1);
        const float* V = src ? v2 : v1;
        float Ax=1.f,Ay=1.f,Az=1.f,Bx=1.f,By=1.f,Bz=1.f,Cx=1.f,Cy=1.f,Cz=1.f;
        if (f < NF_) {
            int i0 = faces[f*3+0], i1 = faces[f*3+1], i2 = faces[f*3+2];
            Ax=V[(b*N_+i0)*3+0]; Ay=V[(b*N_+i0)*3+1]; Az=V[(b*N_+i0)*3+2];
            Bx=V[(b*N_+i1)*3+0]; By=V[(b*N_+i1)*3+1]; Bz=V[(b*N_+i1)*3+2];
            Cx=V[(b*N_+i2)*3+0]; Cy=V[(b*N_+i2)*3+1]; Cz=V[(b*N_+i2)*3+2];
        }
        float Sx = (Ay*Bz - Az*By) + (By*Cz - Bz*Cy) + (Cy*Az - Cz*Ay);
        float Sy = (Az*Bx - Ax*Bz) + (Bz*Cx - Bx*Cz) + (Cz*Ax - Cx*Az);
        float Sz = (Ax*By - Ay*Bx) + (Bx*Cy - By*Cx) + (Cx*Ay - Cy*Ax);
        float det0 = Ax*(By*Cz - Bz*Cy) + Ay*(Bz*Cx - Bx*Cz) + Az*(Bx*Cy - By*Cx);
        float na = Ax*Ax+Ay*Ay+Az*Az, nb = Bx*Bx+By*By+Bz*Bz, nc = Cx*Cx+Cy*Cy+Cz*Cz;
        float qab = Ax*Bx+Ay*By+Az*Bz, qbc = Bx*Cx+By*Cy+Bz*Cz, qca = Cx*Ax+Cy*Ay+Cz*Az;
        float* o = (src ? tbl2 : tbl1) + ((b << 11) + f) * 20;
        o[0]=Ax;  o[1]=Ay;  o[2]=Az;  o[3]=Bx;  o[4]=By;  o[5]=Bz;
        o[6]=Cx;  o[7]=Cy;  o[8]=Cz;  o[9]=-Sx; o[10]=-Sy; o[11]=-Sz;
        o[12]=det0; o[13]=na; o[14]=nb; o[15]=nc;
        o[16]=qab;  o[17]=qbc; o[18]=qca; o[19]=0.f;
    }
}

// per-record solid-angle/2pi given point P(x,y,z) and s=|p|^2 in scope
#define ANG(u0,u1,u2,u3,u4) ({                                               \
    float dAp = fmaf(u0.x,P.x, fmaf(u0.y,P.y, u0.z*P.z));                    \
    float dBp = fmaf(u0.w,P.x, fmaf(u1.x,P.y, u1.y*P.z));                    \
    float dCp = fmaf(u1.z,P.x, fmaf(u1.w,P.y, u2.x*P.z));                    \
    float det = fmaf(u2.y,P.x, fmaf(u2.z,P.y, fmaf(u2.w,P.z, u3.x)));        \
    float la = __builtin_amdgcn_sqrtf(fmaxf(fmaf(-2.f,dAp,u3.y+s),0.f));     \
    float lb = __builtin_amdgcn_sqrtf(fmaxf(fmaf(-2.f,dBp,u3.z+s),0.f));     \
    float lc = __builtin_amdgcn_sqrtf(fmaxf(fmaf(-2.f,dCp,u3.w+s),0.f));     \
    float dab = (u4.x+s)-(dAp+dBp);                                          \
    float dbc = (u4.y+s)-(dBp+dCp);                                          \
    float dca = (u4.z+s)-(dCp+dAp);                                          \
    float denom = fmaf(fmaf(la,lb,dab),lc, fmaf(dbc,la,dca*lb));             \
    atan2_o2pi(det, denom); })

// ---------------------------------------------------------------------------
// mega: winding blocks and rowmin blocks in ONE launch (block-level branch),
// interleaved 16:7 so both kinds co-reside on every CU throughout.
//   winding: lane holds 2 tri records; 64-pt LDS batch; acc rotates (1 shfl).
//   rowmin : lane holds 16 opp records; 64-pt LDS batch; min rotates.
// ---------------------------------------------------------------------------
__global__ __launch_bounds__(256) void mega_kernel(
        const float4* __restrict__ pw1, const float4* __restrict__ pw2,
        const float* __restrict__ tbl1, const float* __restrict__ tbl2,
        const float4* __restrict__ st1, const float4* __restrict__ st2,
        float* __restrict__ part, float* __restrict__ rmp) {
    __shared__ float4 pts[256];
    int bid = blockIdx.x;
    int g = bid / 23, o = bid - g * 23;
    int t = threadIdx.x, wid = t >> 6, lane = t & 63;
    int srcl = (lane + 1) & 63;

    if (o < TCG_) {
        // ---------------- winding ----------------
        int wb   = g * TCG_ + o;              // [0, 1728)
        int pgrp = wb % 27;
        int r    = wb / 27;                   // [0, 64)
        int cg   = r & 15, db = r >> 4;
        int b = db & 1, dir = db >> 1;

        const float4* pw  = dir ? pw2 : pw1;
        const float*  tbl = dir ? tbl1 : tbl2;

        pts[t] = pw[b * NPT_ + pgrp * 256 + t];
        __syncthreads();

#define LREC(nm, j)                                                          \
        const float4* rp##nm = (const float4*)(tbl + (size_t)(b*NFP_ + cg*128 + j*64 + lane)*20); \
        float4 nm##0 = rp##nm[0], nm##1 = rp##nm[1], nm##2 = rp##nm[2],      \
               nm##3 = rp##nm[3], nm##4 = rp##nm[4];
        LREC(A, 0) LREC(Bq, 1)
#undef LREC

        const float4* mypts = pts + wid * 64;
        float acc = 0.f;
        #pragma unroll 2
        for (int k = 0; k < 64; ++k) {
            float4 P = mypts[(lane + k) & 63];
            float s = P.w;
            float g0 = ANG(A0,A1,A2,A3,A4);
            float g1 = ANG(Bq0,Bq1,Bq2,Bq3,Bq4);
            acc += g0 + g1;
            acc = __shfl(acc, srcl, 64);
        }
        part[(db*TCG_ + cg)*NPT_ + pgrp*256 + wid*64 + lane] = acc;
    } else {
        // ---------------- rowmin ----------------
        int rb   = g * OCG_ + (o - TCG_);     // [0, 756)
        int pgrp = rb % 27;
        int r    = rb / 27;                   // [0, 28)
        int ocg  = r % OCG_, db = r / OCG_;
        int b = db & 1, dir = db >> 1;

        const float4* pw = dir ? pw2 : pw1;
        const float4* st = dir ? st1 : st2;

        pts[t] = pw[b * NPT_ + pgrp * 256 + t];
        __syncthreads();

        const float4* qb = st + b * OPP7_ + ocg * 1024;
#define LQ(j) float4 q##j = qb[j*64 + lane];
        LQ(0) LQ(1) LQ(2) LQ(3) LQ(4) LQ(5) LQ(6) LQ(7)
        LQ(8) LQ(9) LQ(10) LQ(11) LQ(12) LQ(13) LQ(14) LQ(15)
#undef LQ

        const float4* mypts = pts + wid * 64;
        float m = 3.4e38f;
        #pragma unroll 2
        for (int k = 0; k < 64; ++k) {
            float4 P = mypts[(lane + k) & 63];
            float s = P.w;
#define DD(j) float d##j = fmaf(q##j.x,P.x, fmaf(q##j.y,P.y, fmaf(q##j.z,P.z, q##j.w + s)));
            DD(0) DD(1) DD(2) DD(3) DD(4) DD(5) DD(6) DD(7)
            DD(8) DD(9) DD(10) DD(11) DD(12) DD(13) DD(14) DD(15)
#undef DD
            float e0 = fminf(d0,d1),  e1 = fminf(d2,d3),  e2 = fminf(d4,d5),  e3 = fminf(d6,d7);
            float e4 = fminf(d8,d9),  e5 = fminf(d10,d11), e6 = fminf(d12,d13), e7 = fminf(d14,d15);
            float f0 = fminf(e0,e1), f1 = fminf(e2,e3), f2 = fminf(e4,e5), f3 = fminf(e6,e7);
            m = fminf(m, fminf(fminf(f0,f1), fminf(f2,f3)));
            m = __shfl(m, srcl, 64);
        }
        rmp[(db*OCG_ + ocg)*NPT_ + pgrp*256 + wid*64 + lane] = m;
    }
}

// ---------------------------------------------------------------------------
// fold: per (db, 256-point group): sum 16 winding partials, min 7 rowmin
// partials, block-reduce masked stats -> pstat[db*27+pg].
// ---------------------------------------------------------------------------
__global__ __launch_bounds__(256) void fold_kernel(
        const float* __restrict__ part, const float* __restrict__ rmp,
        float4* __restrict__ pstat) {
    int pg = blockIdx.x % 27, db = blockIdx.x / 27;
    int t = threadIdx.x, n = pg * 256 + t;

    float ws = 0.f;
    #pragma unroll
    for (int g = 0; g < TCG_; ++g) ws += part[(db*TCG_ + g)*NPT_ + n];
    float rv = 3.4e38f;
    #pragma unroll
    for (int g = 0; g < OCG_; ++g) rv = fminf(rv, rmp[(db*OCG_ + g)*NPT_ + n]);

    bool valid = n < N_;
    float d = sqrtf(rv);
    bool msk = valid && (ws >= 0.99f);
    float v_min = valid ? d : 3.4e38f;
    float v_max = msk ? d : -3.4e38f;
    float v_sum = msk ? d : 0.f;
    float v_cnt = msk ? 1.f : 0.f;

    #pragma unroll
    for (int off = 32; off; off >>= 1) {
        v_min = fminf(v_min, __shfl_down(v_min, off, 64));
        v_max = fmaxf(v_max, __shfl_down(v_max, off, 64));
        v_sum += __shfl_down(v_sum, off, 64);
        v_cnt += __shfl_down(v_cnt, off, 64);
    }
    __shared__ float4 sred[4];
    int wid = t >> 6, lane = t & 63;
    if (lane == 0) sred[wid] = make_float4(v_min, v_max, v_sum, v_cnt);
    __syncthreads();
    if (t == 0) {
        float4 a = sred[0], bb = sred[1], c = sred[2], dd = sred[3];
        pstat[db*27 + pg] = make_float4(
            fminf(fminf(a.x, bb.x), fminf(c.x, dd.x)),
            fmaxf(fmaxf(a.y, bb.y), fmaxf(c.y, dd.y)),
            (a.z + bb.z) + (c.z + dd.z),
            (a.w + bb.w) + (c.w + dd.w));
    }
}

// ---------------------------------------------------------------------------
// final: 1 block, wave w reduces db=w's 27 group stats; thread 0 writes [5][B].
// ---------------------------------------------------------------------------
__global__ void final_kernel(const float4* __restrict__ pstat, float* __restrict__ out) {
    int t = threadIdx.x, wid = t >> 6, lane = t & 63;    // wid = db
    float4 v = make_float4(3.4e38f, -3.4e38f, 0.f, 0.f);
    if (lane < 27) v = pstat[wid*27 + lane];
    #pragma unroll
    for (int off = 32; off; off >>= 1) {
        v.x = fminf(v.x, __shfl_down(v.x, off, 64));
        v.y = fmaxf(v.y, __shfl_down(v.y, off, 64));
        v.z += __shfl_down(v.z, off, 64);
        v.w += __shfl_down(v.w, off, 64);
    }
    __shared__ float4 res[4];
    if (lane == 0) res[wid] = v;
    __syncthreads();
    if (t == 0) {
        #pragma unroll
        for (int b = 0; b < B_; ++b) {
            float4 s1 = res[b], s2 = res[2 + b];
            out[0 + b] = s1.x;
            out[2 + b] = (s1.w > 0.f) ? s1.y : 0.f;
            out[4 + b] = (s1.w > 0.f) ? (s1.z / s1.w) : 0.f;
            out[6 + b] = (s2.w > 0.f) ? s2.y : 0.f;
            out[8 + b] = (s2.w > 0.f) ? (s2.z / s2.w) : 0.f;
        }
    }
}

extern "C" void kernel_launch(void* const* d_in, const int* in_sizes, int n_in,
                              void* d_out, int out_size, void* d_ws, size_t ws_size,
                              hipStream_t stream) {
    const float* v1    = (const float*)d_in[0];
    const float* v2    = (const float*)d_in[1];
    const int*   faces = (const int*)d_in[2];

    float4* f4 = (float4*)d_ws;
    float4* pw1   = f4;                         // B*NPT_  = 13824 f4
    float4* pw2   = pw1 + B_ * NPT_;
    float4* st1   = pw2 + B_ * NPT_;            // B*OPP7_ = 14336 f4
    float4* st2   = st1 + B_ * OPP7_;
    float4* pstat = st2 + B_ * OPP7_;           // 108 f4
    float*  tbl1  = (float*)(pstat + 128);      // B*NFP_*20 = 81920 f
    float*  tbl2  = tbl1 + B_ * NFP_ * 20;
    float*  part  = tbl2 + B_ * NFP_ * 20;      // 4*TCG_*NPT_ = 442368 f
    float*  rmp   = part + 4 * TCG_ * NPT_;     // 4*OCG_*NPT_ = 193536 f
                                                // total ~4.1 MB

    float* out = (float*)d_out;

    prep_kernel<<<(B_ * OPP7_ + 255) / 256, 256, 0, stream>>>(
        v1, v2, faces, pw1, pw2, st1, st2, tbl1, tbl2);

    mega_kernel<<<WBLK_ + RBLK_, 256, 0, stream>>>(
        pw1, pw2, tbl1, tbl2, st1, st2, part, rmp);

    fold_kernel<<<4 * 27, 256, 0, stream>>>(part, rmp, pstat);

    final_kernel<<<1, 256, 0, stream>>>(pstat, out);
}

// Round 9
// 113.949 us; speedup vs baseline: 1.3064x; 1.0049x over previous
//
#include <hip/hip_runtime.h>
#include <math.h>

#define B_     2
#define N_     6890
#define NF_    2000
#define NFP_   2048     // padded triangles: 16 chunks x 128
#define NPT_   6912     // padded points: 27*256
#define OPP7_  7168     // padded opposite cloud: 7 chunks x 1024
#define TCG_   16       // tri chunks (128 tris each, 2 recs/lane)
#define OCG_   7        // opp chunks (1024 recs each, 16 recs/lane)
#define NTILE_ (4 * (TCG_ + OCG_) * 27)   // 2484 logical tiles (23-interleaved)
#define GRID_  2048                        // 8 blocks/CU exactly, persistent

// ---------------------------------------------------------------------------
// atan2(y,x)/(2*pi): branchless octant reduction, single rcp, scale folded in.
// ---------------------------------------------------------------------------
__device__ __forceinline__ float atan2_o2pi(float y, float x) {
    float ax = __builtin_fabsf(x);
    float ay = __builtin_fabsf(y);
    float mx = fmaxf(ax, ay);
    float mn = fminf(ax, ay);
    bool  big = mn > 0.41421356f * mx;
    float num = big ? (mn - mx) : mn;
    float den = big ? (mn + mx) : mx;
    float t   = num * __builtin_amdgcn_rcpf(den);
    float z   = t * t;
    float p   = fmaf(fmaf(fmaf(1.2817932e-2f, z, -2.2087019e-2f), z,
                          3.1795514e-2f), z, -5.3051037e-2f);   // coeffs / 2pi
    float r   = fmaf(t, fmaf(z, p, 0.15915494309f), big ? 0.125f : 0.0f);
    r = (ay > ax)  ? 0.25f - r : r;
    r = (x < 0.0f) ? 0.5f  - r : r;
    return copysignf(r, y);
}

// ---------------------------------------------------------------------------
// prep (layouts unchanged):
//  pw[b][n] = (x,y,z,|p|^2)        pad zeros              [B][NPT_]
//  st[b][n] = (-2x,-2y,-2z,|o|^2)  pad (0,0,0,1e30)       [B][OPP7_]
//  tbl[b][f][20] = [A,B,C, -S, det0, na,nb,nc, qab,qbc,qca, 0]
// ---------------------------------------------------------------------------
__global__ void prep_kernel(const float* __restrict__ v1, const float* __restrict__ v2,
                            const int* __restrict__ faces,
                            float4* __restrict__ pw1, float4* __restrict__ pw2,
                            float4* __restrict__ st1, float4* __restrict__ st2,
                            float* __restrict__ tbl1, float* __restrict__ tbl2) {
    int tid = blockIdx.x * 256 + threadIdx.x;

    if (tid < B_ * NPT_) {
        int b = tid / NPT_, n = tid - b * NPT_;
        float4 q1 = make_float4(0.f, 0.f, 0.f, 0.f), q2 = q1;
        if (n < N_) {
            float x1 = v1[(b*N_+n)*3+0], y1 = v1[(b*N_+n)*3+1], z1 = v1[(b*N_+n)*3+2];
            float x2 = v2[(b*N_+n)*3+0], y2 = v2[(b*N_+n)*3+1], z2 = v2[(b*N_+n)*3+2];
            q1 = make_float4(x1, y1, z1, fmaf(x1,x1, fmaf(y1,y1, z1*z1)));
            q2 = make_float4(x2, y2, z2, fmaf(x2,x2, fmaf(y2,y2, z2*z2)));
        }
        pw1[tid] = q1; pw2[tid] = q2;
    }

    if (tid < B_ * OPP7_) {
        int b = tid / OPP7_, n = tid - b * OPP7_;
        float4 q1 = make_float4(0.f, 0.f, 0.f, 1e30f), q2 = q1;
        if (n < N_) {
            float x1 = v1[(b*N_+n)*3+0], y1 = v1[(b*N_+n)*3+1], z1 = v1[(b*N_+n)*3+2];
            float x2 = v2[(b*N_+n)*3+0], y2 = v2[(b*N_+n)*3+1], z2 = v2[(b*N_+n)*3+2];
            q1 = make_float4(-2.f*x1, -2.f*y1, -2.f*z1, fmaf(x1,x1, fmaf(y1,y1, z1*z1)));
            q2 = make_float4(-2.f*x2, -2.f*y2, -2.f*z2, fmaf(x2,x2, fmaf(y2,y2, z2*z2)));
        }
        st1[tid] = q1; st2[tid] = q2;
    }

    if (tid < 2 * B_ * NFP_) {
        int src = tid >> 12;
        int rr  = tid & (B_ * NFP_ - 1);
        int b   = rr >> 11;
        int f   = rr & (NFP_ - 1);
        const float* V = src ? v2 : v1;
        float Ax=1.f,Ay=1.f,Az=1.f,Bx=1.f,By=1.f,Bz=1.f,Cx=1.f,Cy=1.f,Cz=1.f;
        if (f < NF_) {
            int i0 = faces[f*3+0], i1 = faces[f*3+1], i2 = faces[f*3+2];
            Ax=V[(b*N_+i0)*3+0]; Ay=V[(b*N_+i0)*3+1]; Az=V[(b*N_+i0)*3+2];
            Bx=V[(b*N_+i1)*3+0]; By=V[(b*N_+i1)*3+1]; Bz=V[(b*N_+i1)*3+2];
            Cx=V[(b*N_+i2)*3+0]; Cy=V[(b*N_+i2)*3+1]; Cz=V[(b*N_+i2)*3+2];
        }
        float Sx = (Ay*Bz - Az*By) + (By*Cz - Bz*Cy) + (Cy*Az - Cz*Ay);
        float Sy = (Az*Bx - Ax*Bz) + (Bz*Cx - Bx*Cz) + (Cz*Ax - Cx*Az);
        float Sz = (Ax*By - Ay*Bx) + (Bx*Cy - By*Cx) + (Cx*Ay - Cy*Ax);
        float det0 = Ax*(By*Cz - Bz*Cy) + Ay*(Bz*Cx - Bx*Cz) + Az*(Bx*Cy - By*Cx);
        float na = Ax*Ax+Ay*Ay+Az*Az, nb = Bx*Bx+By*By+Bz*Bz, nc = Cx*Cx+Cy*Cy+Cz*Cz;
        float qab = Ax*Bx+Ay*By+Az*Bz, qbc = Bx*Cx+By*Cy+Bz*Cz, qca = Cx*Ax+Cy*Ay+Cz*Az;
        float* o = (src ? tbl2 : tbl1) + ((b << 11) + f) * 20;
        o[0]=Ax;  o[1]=Ay;  o[2]=Az;  o[3]=Bx;  o[4]=By;  o[5]=Bz;
        o[6]=Cx;  o[7]=Cy;  o[8]=Cz;  o[9]=-Sx; o[10]=-Sy; o[11]=-Sz;
        o[12]=det0; o[13]=na; o[14]=nb; o[15]=nc;
        o[16]=qab;  o[17]=qbc; o[18]=qca; o[19]=0.f;
    }
}

// per-record solid-angle/2pi given point P(x,y,z) and s=|p|^2 in scope
#define ANG(u0,u1,u2,u3,u4) ({                                               \
    float dAp = fmaf(u0.x,P.x, fmaf(u0.y,P.y, u0.z*P.z));                    \
    float dBp = fmaf(u0.w,P.x, fmaf(u1.x,P.y, u1.y*P.z));                    \
    float dCp = fmaf(u1.z,P.x, fmaf(u1.w,P.y, u2.x*P.z));                    \
    float det = fmaf(u2.y,P.x, fmaf(u2.z,P.y, fmaf(u2.w,P.z, u3.x)));        \
    float la = __builtin_amdgcn_sqrtf(fmaxf(fmaf(-2.f,dAp,u3.y+s),0.f));     \
    float lb = __builtin_amdgcn_sqrtf(fmaxf(fmaf(-2.f,dBp,u3.z+s),0.f));     \
    float lc = __builtin_amdgcn_sqrtf(fmaxf(fmaf(-2.f,dCp,u3.w+s),0.f));     \
    float dab = (u4.x+s)-(dAp+dBp);                                          \
    float dbc = (u4.y+s)-(dBp+dCp);                                          \
    float dca = (u4.z+s)-(dCp+dAp);                                          \
    float denom = fmaf(fmaf(la,lb,dab),lc, fmaf(dbc,la,dca*lb));             \
    atan2_o2pi(det, denom); })

// ---------------------------------------------------------------------------
// mega (persistent): 2048 blocks, grid-stride over 2484 tiles (23-interleave:
// per group of 23, tiles 0..15 = winding chunks, 16..22 = rowmin chunks).
//   winding: lane holds 2 tri records; 64-pt LDS batch; acc rotates (1 shfl).
//   rowmin : lane holds 16 opp records; 64-pt LDS batch; min rotates;
//            |p|^2 hoisted out of the 16-record fma chain.
// ---------------------------------------------------------------------------
__global__ __launch_bounds__(256) void mega_kernel(
        const float4* __restrict__ pw1, const float4* __restrict__ pw2,
        const float* __restrict__ tbl1, const float* __restrict__ tbl2,
        const float4* __restrict__ st1, const float4* __restrict__ st2,
        float* __restrict__ part, float* __restrict__ rmp) {
    __shared__ float4 pts[256];
    int t = threadIdx.x, wid = t >> 6, lane = t & 63;
    int srcl = (lane + 1) & 63;

    for (int tile = blockIdx.x; tile < NTILE_; tile += GRID_) {
        int g = tile / 23, o = tile - g * 23;
        __syncthreads();   // protect pts from previous tile's readers

        if (o < TCG_) {
            // ---------------- winding ----------------
            int wb   = g * TCG_ + o;              // [0, 1728)
            int pgrp = wb % 27;
            int r    = wb / 27;                   // [0, 64)
            int cg   = r & 15, db = r >> 4;
            int b = db & 1, dir = db >> 1;

            const float4* pw  = dir ? pw2 : pw1;
            const float*  tbl = dir ? tbl1 : tbl2;

            pts[t] = pw[b * NPT_ + pgrp * 256 + t];
            __syncthreads();

#define LREC(nm, j)                                                          \
            const float4* rp##nm = (const float4*)(tbl + (size_t)(b*NFP_ + cg*128 + j*64 + lane)*20); \
            float4 nm##0 = rp##nm[0], nm##1 = rp##nm[1], nm##2 = rp##nm[2],  \
                   nm##3 = rp##nm[3], nm##4 = rp##nm[4];
            LREC(A, 0) LREC(Bq, 1)
#undef LREC

            const float4* mypts = pts + wid * 64;
            float acc = 0.f;
            #pragma unroll 2
            for (int k = 0; k < 64; ++k) {
                float4 P = mypts[(lane + k) & 63];
                float s = P.w;
                float g0 = ANG(A0,A1,A2,A3,A4);
                float g1 = ANG(Bq0,Bq1,Bq2,Bq3,Bq4);
                acc += g0 + g1;
                acc = __shfl(acc, srcl, 64);
            }
            part[(db*TCG_ + cg)*NPT_ + pgrp*256 + wid*64 + lane] = acc;
        } else {
            // ---------------- rowmin ----------------
            int rb   = g * OCG_ + (o - TCG_);     // [0, 756)
            int pgrp = rb % 27;
            int r    = rb / 27;                   // [0, 28)
            int ocg  = r % OCG_, db = r / OCG_;
            int b = db & 1, dir = db >> 1;

            const float4* pw = dir ? pw2 : pw1;
            const float4* st = dir ? st1 : st2;

            pts[t] = pw[b * NPT_ + pgrp * 256 + t];
            __syncthreads();

            const float4* qb = st + b * OPP7_ + ocg * 1024;
#define LQ(j) float4 q##j = qb[j*64 + lane];
            LQ(0) LQ(1) LQ(2) LQ(3) LQ(4) LQ(5) LQ(6) LQ(7)
            LQ(8) LQ(9) LQ(10) LQ(11) LQ(12) LQ(13) LQ(14) LQ(15)
#undef LQ

            const float4* mypts = pts + wid * 64;
            float m = 3.4e38f;
            #pragma unroll 2
            for (int k = 0; k < 64; ++k) {
                float4 P = mypts[(lane + k) & 63];
                float s = P.w;
#define DD(j) float d##j = fmaf(q##j.x,P.x, fmaf(q##j.y,P.y, fmaf(q##j.z,P.z, q##j.w)));
                DD(0) DD(1) DD(2) DD(3) DD(4) DD(5) DD(6) DD(7)
                DD(8) DD(9) DD(10) DD(11) DD(12) DD(13) DD(14) DD(15)
#undef DD
                float e0 = fminf(d0,d1),  e1 = fminf(d2,d3),  e2 = fminf(d4,d5),  e3 = fminf(d6,d7);
                float e4 = fminf(d8,d9),  e5 = fminf(d10,d11), e6 = fminf(d12,d13), e7 = fminf(d14,d15);
                float f0 = fminf(e0,e1), f1 = fminf(e2,e3), f2 = fminf(e4,e5), f3 = fminf(e6,e7);
                float h  = fminf(fminf(f0,f1), fminf(f2,f3));
                m = fminf(m, h + s);               // |p|^2 hoisted out of fmas
                m = __shfl(m, srcl, 64);
            }
            rmp[(db*OCG_ + ocg)*NPT_ + pgrp*256 + wid*64 + lane] = m;
        }
    }
}

// ---------------------------------------------------------------------------
// fold: per (db, 256-point group): sum 16 winding partials, min 7 rowmin
// partials, block-reduce masked stats -> pstat[db*27+pg].
// ---------------------------------------------------------------------------
__global__ __launch_bounds__(256) void fold_kernel(
        const float* __restrict__ part, const float* __restrict__ rmp,
        float4* __restrict__ pstat) {
    int pg = blockIdx.x % 27, db = blockIdx.x / 27;
    int t = threadIdx.x, n = pg * 256 + t;

    float ws = 0.f;
    #pragma unroll
    for (int g = 0; g < TCG_; ++g) ws += part[(db*TCG_ + g)*NPT_ + n];
    float rv = 3.4e38f;
    #pragma unroll
    for (int g = 0; g < OCG_; ++g) rv = fminf(rv, rmp[(db*OCG_ + g)*NPT_ + n]);

    bool valid = n < N_;
    float d = sqrtf(rv);
    bool msk = valid && (ws >= 0.99f);
    float v_min = valid ? d : 3.4e38f;
    float v_max = msk ? d : -3.4e38f;
    float v_sum = msk ? d : 0.f;
    float v_cnt = msk ? 1.f : 0.f;

    #pragma unroll
    for (int off = 32; off; off >>= 1) {
        v_min = fminf(v_min, __shfl_down(v_min, off, 64));
        v_max = fmaxf(v_max, __shfl_down(v_max, off, 64));
        v_sum += __shfl_down(v_sum, off, 64);
        v_cnt += __shfl_down(v_cnt, off, 64);
    }
    __shared__ float4 sred[4];
    int wid = t >> 6, lane = t & 63;
    if (lane == 0) sred[wid] = make_float4(v_min, v_max, v_sum, v_cnt);
    __syncthreads();
    if (t == 0) {
        float4 a = sred[0], bb = sred[1], c = sred[2], dd = sred[3];
        pstat[db*27 + pg] = make_float4(
            fminf(fminf(a.x, bb.x), fminf(c.x, dd.x)),
            fmaxf(fmaxf(a.y, bb.y), fmaxf(c.y, dd.y)),
            (a.z + bb.z) + (c.z + dd.z),
            (a.w + bb.w) + (c.w + dd.w));
    }
}

// ---------------------------------------------------------------------------
// final: 1 block, wave w reduces db=w's 27 group stats; thread 0 writes [5][B].
// ---------------------------------------------------------------------------
__global__ void final_kernel(const float4* __restrict__ pstat, float* __restrict__ out) {
    int t = threadIdx.x, wid = t >> 6, lane = t & 63;    // wid = db
    float4 v = make_float4(3.4e38f, -3.4e38f, 0.f, 0.f);
    if (lane < 27) v = pstat[wid*27 + lane];
    #pragma unroll
    for (int off = 32; off; off >>= 1) {
        v.x = fminf(v.x, __shfl_down(v.x, off, 64));
        v.y = fmaxf(v.y, __shfl_down(v.y, off, 64));
        v.z += __shfl_down(v.z, off, 64);
        v.w += __shfl_down(v.w, off, 64);
    }
    __shared__ float4 res[4];
    if (lane == 0) res[wid] = v;
    __syncthreads();
    if (t == 0) {
        #pragma unroll
        for (int b = 0; b < B_; ++b) {
            float4 s1 = res[b], s2 = res[2 + b];
            out[0 + b] = s1.x;
            out[2 + b] = (s1.w > 0.f) ? s1.y : 0.f;
            out[4 + b] = (s1.w > 0.f) ? (s1.z / s1.w) : 0.f;
            out[6 + b] = (s2.w > 0.f) ? s2.y : 0.f;
            out[8 + b] = (s2.w > 0.f) ? (s2.z / s2.w) : 0.f;
        }
    }
}

extern "C" void kernel_launch(void* const* d_in, const int* in_sizes, int n_in,
                              void* d_out, int out_size, void* d_ws, size_t ws_size,
                              hipStream_t stream) {
    const float* v1    = (const float*)d_in[0];
    const float* v2    = (const float*)d_in[1];
    const int*   faces = (const int*)d_in[2];

    float4* f4 = (float4*)d_ws;
    float4* pw1   = f4;                         // B*NPT_  = 13824 f4
    float4* pw2   = pw1 + B_ * NPT_;
    float4* st1   = pw2 + B_ * NPT_;            // B*OPP7_ = 14336 f4
    float4* st2   = st1 + B_ * OPP7_;
    float4* pstat = st2 + B_ * OPP7_;           // 108 f4
    float*  tbl1  = (float*)(pstat + 128);      // B*NFP_*20 = 81920 f
    float*  tbl2  = tbl1 + B_ * NFP_ * 20;
    float*  part  = tbl2 + B_ * NFP_ * 20;      // 4*TCG_*NPT_ = 442368 f
    float*  rmp   = part + 4 * TCG_ * NPT_;     // 4*OCG_*NPT_ = 193536 f
                                                // total ~4.1 MB

    float* out = (float*)d_out;

    prep_kernel<<<(B_ * OPP7_ + 255) / 256, 256, 0, stream>>>(
        v1, v2, faces, pw1, pw2, st1, st2, tbl1, tbl2);

    mega_kernel<<<GRID_, 256, 0, stream>>>(
        pw1, pw2, tbl1, tbl2, st1, st2, part, rmp);

    fold_kernel<<<4 * 27, 256, 0, stream>>>(part, rmp, pstat);

    final_kernel<<<1, 256, 0, stream>>>(pstat, out);
}